// Round 9
// baseline (66.262 us; speedup 1.0000x reference)
//
#include <hip/hip_runtime.h>

// Chamfer distance, N=M=16384, D=3, f32 — packed-fp32 VALU kernel.
// min_j dist(p,q_j) = -2*( max_j (dot(p,q_j) - 0.5|q_j|^2) - 0.5|p|^2 ), >= 0.
// R8: after R3-R7 showed hipcc can't feed MFMA without AGPR-shuttle/spill
// (best 49us), return to the issue-bound scalar kernel (R2: 43us @107%
// VALUBusy) and HALVE the issue count with v_pk_fma_f32 (dual-rate packed
// fp32 — the 157.3TF spec = 2x wave64-scalar rate). Two q-points per
// instruction: 3 v_pk_fma + 1 v_max3(m, acc.lo, acc.hi) = 4 instr / 2 pairs.
// q-side stored pair-SoA so the wave-uniform LDS read is 2 ds_read_b128 per
// q-pair, amortized over T=8 owners.

typedef float f32x2 __attribute__((ext_vector_type(2)));

#define NPTS   16384
#define TPB    256
#define T      8                 // owner points per thread
#define SLICES 128               // q slices per direction
#define LQ     (NPTS / SLICES)   // 128 q per slice
#define PAIRS  (LQ / 2)          // 64 q-pairs per slice (2 KB LDS)

// Per point: owner-form float4 (x,y,z,+0.5|v|^2) and q-form pair-SoA
// [pair]{x0,x1,y0,y1,z0,z1,-h0,-h1}; init min arrays to +inf every call
// (graph replay must be deterministic).
__global__ __launch_bounds__(TPB) void cd_prep(
        const float* __restrict__ x, const float* __restrict__ y,
        float4* __restrict__ xp, float4* __restrict__ yp,
        float* __restrict__ xq, float* __restrict__ yq,
        unsigned* __restrict__ minx, unsigned* __restrict__ miny, int n, int m) {
    int i = blockIdx.x * TPB + threadIdx.x;
    if (i >= n + m) return;
    const float* src = (i < n) ? x : y;
    int k = (i < n) ? i : i - n;
    float a = src[3 * k], b = src[3 * k + 1], c = src[3 * k + 2];
    float half = 0.5f * (a * a + b * b + c * c);
    float4* pp = (i < n) ? xp : yp;
    float* qq = (i < n) ? xq : yq;
    unsigned* mn = (i < n) ? minx : miny;
    pp[k] = make_float4(a, b, c, half);
    int base = (k >> 1) * 8 + (k & 1);
    qq[base + 0] = a;
    qq[base + 2] = b;
    qq[base + 4] = c;
    qq[base + 6] = -half;
    mn[k] = 0x7f800000u;  // +inf
}

// blockIdx = (owner-block, q-slice, direction). Stage the slice's pair-SoA
// (2 KB) in LDS; each thread: 8 owners (pre-broadcast float2 coords) x 64
// q-pairs; per pair-group 2 broadcast ds_read_b128 + per owner {3 v_pk_fma +
// 1 v_max3}. Slice partials via uint atomicMin (distances >= 0: float order
// == uint bit order).
__global__ __launch_bounds__(TPB) void cd_pass(
        const float4* __restrict__ xp, const float4* __restrict__ yp,
        const float* __restrict__ xq, const float* __restrict__ yq,
        unsigned* __restrict__ minx, unsigned* __restrict__ miny) {
    const float4* P; const float* Q; unsigned* out;
    if (blockIdx.z == 0) { P = xp; Q = yq; out = minx; }  // owners=x vs q=y
    else                 { P = yp; Q = xq; out = miny; }  // owners=y vs q=x

    __shared__ __align__(16) float qs[LQ * 4];
    const int j0 = blockIdx.y * LQ;
    const float4* srcq = (const float4*)(Q + (size_t)j0 * 4);
    if (threadIdx.x < PAIRS * 2) ((float4*)qs)[threadIdx.x] = srcq[threadIdx.x];
    __syncthreads();

    const int base = blockIdx.x * (TPB * T) + threadIdx.x;
    f32x2 px[T], py[T], pz[T];
    float ph[T], m[T];
#pragma unroll
    for (int k = 0; k < T; ++k) {
        float4 p = P[base + k * TPB];
        px[k] = (f32x2){p.x, p.x};
        py[k] = (f32x2){p.y, p.y};
        pz[k] = (f32x2){p.z, p.z};
        ph[k] = p.w;
        m[k] = -INFINITY;
    }

#pragma unroll 4
    for (int jp = 0; jp < PAIRS; ++jp) {
        // wave-uniform -> broadcast; 4x f32x2 merge into 2 ds_read_b128
        f32x2 qx2 = *(const f32x2*)(qs + jp * 8 + 0);
        f32x2 qy2 = *(const f32x2*)(qs + jp * 8 + 2);
        f32x2 qz2 = *(const f32x2*)(qs + jp * 8 + 4);
        f32x2 qw2 = *(const f32x2*)(qs + jp * 8 + 6);
#pragma unroll
        for (int k = 0; k < T; ++k) {
            f32x2 acc;
            asm("v_pk_fma_f32 %0, %1, %2, %3\n\t"
                "v_pk_fma_f32 %0, %4, %5, %0\n\t"
                "v_pk_fma_f32 %0, %6, %7, %0"
                : "=&v"(acc)
                : "v"(px[k]), "v"(qx2), "v"(qw2),
                  "v"(py[k]), "v"(qy2),
                  "v"(pz[k]), "v"(qz2));
            m[k] = fmaxf(m[k], fmaxf(acc.x, acc.y));  // -> v_max3
        }
    }

#pragma unroll
    for (int k = 0; k < T; ++k) {
        float d = fmaxf(0.0f, 2.0f * (ph[k] - m[k]));
        atomicMin(&out[base + k * TPB], __float_as_uint(d));
    }
}

// Single-block final reduction: mean of minx[N] ++ miny[M].
__global__ __launch_bounds__(1024) void cd_reduce(const uint4* __restrict__ minx,
                                                  const uint4* __restrict__ miny,
                                                  float* __restrict__ out, int n, int mm) {
    float s = 0.0f;
    for (int i = threadIdx.x; i < n / 4; i += 1024) {
        uint4 v = minx[i];
        s += __uint_as_float(v.x) + __uint_as_float(v.y) +
             __uint_as_float(v.z) + __uint_as_float(v.w);
    }
    for (int i = threadIdx.x; i < mm / 4; i += 1024) {
        uint4 v = miny[i];
        s += __uint_as_float(v.x) + __uint_as_float(v.y) +
             __uint_as_float(v.z) + __uint_as_float(v.w);
    }
    for (int off = 32; off >= 1; off >>= 1) s += __shfl_down(s, off, 64);
    __shared__ float wsum[16];
    int wave = threadIdx.x >> 6;
    int lane = threadIdx.x & 63;
    if (lane == 0) wsum[wave] = s;
    __syncthreads();
    if (threadIdx.x == 0) {
        float t = 0.0f;
        for (int w = 0; w < 16; ++w) t += wsum[w];
        out[0] = t / (float)(n + mm);
    }
}

extern "C" void kernel_launch(void* const* d_in, const int* in_sizes, int n_in,
                              void* d_out, int out_size, void* d_ws, size_t ws_size,
                              hipStream_t stream) {
    const float* x = (const float*)d_in[0];
    const float* y = (const float*)d_in[1];
    const int N = in_sizes[0] / 3;  // 16384
    const int M = in_sizes[1] / 3;  // 16384

    float4* xp = (float4*)d_ws;                    // N float4 (owner form)
    float4* yp = xp + N;                           // M float4
    float* xq = (float*)(yp + M);                  // N*4 floats (pair-SoA)
    float* yq = xq + (size_t)N * 4;                // M*4 floats
    unsigned* minx = (unsigned*)(yq + (size_t)M * 4);  // N uint
    unsigned* miny = minx + N;                     // M uint
    float* out = (float*)d_out;

    cd_prep<<<(N + M + TPB - 1) / TPB, TPB, 0, stream>>>(x, y, xp, yp, xq, yq,
                                                         minx, miny, N, M);

    // grid: (owner blocks, q slices, direction) = (8, 128, 2) = 2048 blocks
    cd_pass<<<dim3(NPTS / (TPB * T), SLICES, 2), TPB, 0, stream>>>(xp, yp, xq, yq,
                                                                   minx, miny);

    cd_reduce<<<1, 1024, 0, stream>>>((const uint4*)minx, (const uint4*)miny, out, N, M);
}